// Round 1
// baseline (1165.789 us; speedup 1.0000x reference)
//
#include <hip/hip_runtime.h>

#define CIRC 10000
#define DIS  4000
#define LAT  64
#define EPSF 1e-8f

// ---------------- degree kernels ----------------
__global__ __launch_bounds__(256) void rowsum_kernel(const float* __restrict__ A,
                                                     float* __restrict__ dc) {
    int wid = threadIdx.x >> 6, lane = threadIdx.x & 63;
    int r = blockIdx.x * 4 + wid;
    if (r >= CIRC) return;
    const float4* row = (const float4*)(A + (size_t)r * DIS);
    float s = 0.f;
    for (int c4 = lane; c4 < DIS / 4; c4 += 64) {
        float4 v = row[c4];
        s += v.x + v.y + v.z + v.w;
    }
    #pragma unroll
    for (int o = 32; o; o >>= 1) s += __shfl_down(s, o);
    if (lane == 0) dc[r] = s;
}

__global__ __launch_bounds__(256) void colsum_kernel(const float* __restrict__ A,
                                                     float* __restrict__ dd) {
    int c = blockIdx.x * 256 + threadIdx.x;
    if (c >= DIS) return;
    int r0 = blockIdx.y * 250;
    float s = 0.f;
    for (int r = r0; r < r0 + 250; ++r) s += A[(size_t)r * DIS + c];
    atomicAdd(&dd[c], s);
}

__global__ __launch_bounds__(256) void inv_kernel(float* __restrict__ dc, float* __restrict__ dd) {
    int i = blockIdx.x * 256 + threadIdx.x;
    if (i < CIRC) {
        float v = dc[i];
        dc[i] = (v > 0.f) ? rsqrtf(fmaxf(v, EPSF)) : 0.f;
    } else if (i < CIRC + DIS) {
        int j = i - CIRC;
        float v = dd[j];
        dd[j] = (v > 0.f) ? rsqrtf(fmaxf(v, EPSF)) : 0.f;
    }
}

// Bc[i][j] = inv_c[i]*circ[i][j]; Bd[c][j] = inv_d[c]*dis[c][j]; acc = 0
__global__ __launch_bounds__(256) void init_kernel(const float* __restrict__ circ,
                                                   const float* __restrict__ dis,
                                                   const float* __restrict__ inv_c,
                                                   const float* __restrict__ inv_d,
                                                   float* __restrict__ Bc, float* __restrict__ Bd,
                                                   float* __restrict__ acc) {
    int idx = blockIdx.x * 256 + threadIdx.x;
    if (idx >= (CIRC + DIS) * LAT) return;
    int r = idx >> 6;
    if (r < CIRC) {
        Bc[idx] = inv_c[r] * circ[idx];
    } else {
        int cidx = idx - CIRC * LAT;
        Bd[cidx] = inv_d[r - CIRC] * dis[cidx];
    }
    acc[idx] = 0.f;
}

// ---------------- tall-skinny SGEMM: C[m][64] += sum_k Aop[m,k]*B[k][64] ----------------
// Aop[m,k] = TRANS ? Ag[k*DIS + m] : Ag[m*DIS + k]
// BM=128, BK=16, block=256, per-thread 8x4, split-K via blockIdx.y (atomicAdd epilogue)
template <bool TRANS>
__global__ __launch_bounds__(256) void gemm_tn(const float* __restrict__ Ag,
                                               const float* __restrict__ B,
                                               float* __restrict__ C,
                                               int M, int K, int KC) {
    __shared__ float As[16][132];   // [k][m], +4 pad keeps 16B align & spreads banks
    __shared__ float Bs[16][64];    // [k][j]
    const int t  = threadIdx.x;
    const int tx = t & 15, ty = t >> 4;
    const int m0 = blockIdx.x * 128;
    const int kbeg = blockIdx.y * KC;
    const int kend = (kbeg + KC < K) ? (kbeg + KC) : K;

    float acc[8][4];
    #pragma unroll
    for (int i = 0; i < 8; ++i)
        #pragma unroll
        for (int j = 0; j < 4; ++j) acc[i][j] = 0.f;

    for (int k0 = kbeg; k0 < kend; k0 += 16) {
        const int klen = kend - k0;   // 16 except possibly last chunk
        if (TRANS) {
            #pragma unroll
            for (int p = 0; p < 2; ++p) {
                int q  = t + (p << 8);       // 512 float4 slots = 16k x 32
                int kk = q >> 5;
                int mv = (q & 31) << 2;
                float4 v = make_float4(0.f, 0.f, 0.f, 0.f);
                int m = m0 + mv;
                if (kk < klen && m < M)
                    v = *(const float4*)(Ag + (size_t)(k0 + kk) * DIS + m);
                *(float4*)&As[kk][mv] = v;
            }
        } else {
            #pragma unroll
            for (int p = 0; p < 2; ++p) {
                int q  = t + (p << 8);       // 512 float4 slots = 128m x 4kv
                int mm = q >> 2;
                int kv = (q & 3) << 2;
                float4 v = make_float4(0.f, 0.f, 0.f, 0.f);
                int m = m0 + mm;
                if (m < M && kv < klen)      // klen always multiple of 4 here (KC%4==0)
                    v = *(const float4*)(Ag + (size_t)m * DIS + k0 + kv);
                As[kv + 0][mm] = v.x;
                As[kv + 1][mm] = v.y;
                As[kv + 2][mm] = v.z;
                As[kv + 3][mm] = v.w;
            }
        }
        {
            int kk = t >> 4, jv = (t & 15) << 2;
            float4 v = make_float4(0.f, 0.f, 0.f, 0.f);
            if (kk < klen) v = *(const float4*)(B + (size_t)(k0 + kk) * LAT + jv);
            *(float4*)&Bs[kk][jv] = v;
        }
        __syncthreads();
        #pragma unroll
        for (int kk = 0; kk < 16; ++kk) {
            float4 a0 = *(float4*)&As[kk][ty * 8];
            float4 a1 = *(float4*)&As[kk][ty * 8 + 4];
            float4 bv = *(float4*)&Bs[kk][tx * 4];
            float af[8] = {a0.x, a0.y, a0.z, a0.w, a1.x, a1.y, a1.z, a1.w};
            float bf[4] = {bv.x, bv.y, bv.z, bv.w};
            #pragma unroll
            for (int i = 0; i < 8; ++i)
                #pragma unroll
                for (int j = 0; j < 4; ++j) acc[i][j] = fmaf(af[i], bf[j], acc[i][j]);
        }
        __syncthreads();
    }
    #pragma unroll
    for (int i = 0; i < 8; ++i) {
        int m = m0 + ty * 8 + i;
        if (m < M) {
            #pragma unroll
            for (int j = 0; j < 4; ++j)
                atomicAdd(&C[(size_t)m * LAT + tx * 4 + j], acc[i][j]);
        }
    }
}

// ---------------- per-row cosine weight + accumulate + prep next-layer inputs ----------------
__global__ __launch_bounds__(256) void update_kernel(const float* __restrict__ gA,
                                                     const float* __restrict__ gB,
                                                     const float* __restrict__ inv_c,
                                                     const float* __restrict__ inv_d,
                                                     const float* __restrict__ circ,
                                                     const float* __restrict__ dis,
                                                     float* __restrict__ Bc, float* __restrict__ Bd,
                                                     float* __restrict__ acc) {
    int wid = threadIdx.x >> 6, lane = threadIdx.x & 63;
    int r = blockIdx.x * 4 + wid;
    if (r >= CIRC + DIS) return;
    float raw, ego, scale;
    if (r < CIRC) {
        scale = inv_c[r];
        raw = scale * gA[(size_t)r * LAT + lane];
        ego = circ[(size_t)r * LAT + lane];
    } else {
        int c = r - CIRC;
        scale = inv_d[c];
        raw = scale * gB[(size_t)c * LAT + lane];
        ego = dis[(size_t)c * LAT + lane];
    }
    float dot = raw * ego, n1 = raw * raw, n2 = ego * ego;
    #pragma unroll
    for (int o = 32; o; o >>= 1) {
        dot += __shfl_down(dot, o);
        n1  += __shfl_down(n1, o);
        n2  += __shfl_down(n2, o);
    }
    dot = __shfl(dot, 0); n1 = __shfl(n1, 0); n2 = __shfl(n2, 0);
    float w = dot / (fmaxf(sqrtf(n1), EPSF) * fmaxf(sqrtf(n2), EPSF));
    float val = w * raw;
    acc[(size_t)r * LAT + lane] += val;
    if (r < CIRC) Bc[(size_t)r * LAT + lane] = scale * val;
    else          Bd[(size_t)(r - CIRC) * LAT + lane] = scale * val;
}

// ---------------- predict = (circ_all * diag) @ dis_all^T, tile 128x64, K=64 ----------------
__global__ __launch_bounds__(256) void predict_kernel(const float* __restrict__ acc,
                                                      const float* __restrict__ reCD,
                                                      float* __restrict__ outp) {
    __shared__ float XsT[64][132];  // [l][i]  (circ rows, scaled by diag)
    __shared__ float YsT[64][68];   // [l][j]  (dis rows)
    __shared__ float dl[64];
    const int t = threadIdx.x;
    const int i0 = blockIdx.x * 128;
    const int j0 = blockIdx.y * 64;
    const float* circ_all = acc;
    const float* dis_all  = acc + (size_t)CIRC * LAT;
    if (t < 64) dl[t] = reCD[t * 65];   // diagonal of 64x64
    __syncthreads();
    #pragma unroll
    for (int p = 0; p < 8; ++p) {
        int q  = t + (p << 8);
        int ii = q >> 4;               // 0..127
        int lv = (q & 15) << 2;        // 0..60
        float4 v = make_float4(0.f, 0.f, 0.f, 0.f);
        if (i0 + ii < CIRC) v = *(const float4*)(circ_all + (size_t)(i0 + ii) * LAT + lv);
        XsT[lv + 0][ii] = v.x * dl[lv + 0];
        XsT[lv + 1][ii] = v.y * dl[lv + 1];
        XsT[lv + 2][ii] = v.z * dl[lv + 2];
        XsT[lv + 3][ii] = v.w * dl[lv + 3];
        if (p < 4) {
            int jj = ii;               // 0..63
            float4 u = make_float4(0.f, 0.f, 0.f, 0.f);
            if (j0 + jj < DIS) u = *(const float4*)(dis_all + (size_t)(j0 + jj) * LAT + lv);
            YsT[lv + 0][jj] = u.x;
            YsT[lv + 1][jj] = u.y;
            YsT[lv + 2][jj] = u.z;
            YsT[lv + 3][jj] = u.w;
        }
    }
    __syncthreads();
    const int tx = t & 15, ty = t >> 4;
    float accv[8][4];
    #pragma unroll
    for (int i = 0; i < 8; ++i)
        #pragma unroll
        for (int j = 0; j < 4; ++j) accv[i][j] = 0.f;
    #pragma unroll 8
    for (int l = 0; l < 64; ++l) {
        float4 a0 = *(float4*)&XsT[l][ty * 8];
        float4 a1 = *(float4*)&XsT[l][ty * 8 + 4];
        float4 bv = *(float4*)&YsT[l][tx * 4];
        float af[8] = {a0.x, a0.y, a0.z, a0.w, a1.x, a1.y, a1.z, a1.w};
        float bf[4] = {bv.x, bv.y, bv.z, bv.w};
        #pragma unroll
        for (int i = 0; i < 8; ++i)
            #pragma unroll
            for (int j = 0; j < 4; ++j) accv[i][j] = fmaf(af[i], bf[j], accv[i][j]);
    }
    #pragma unroll
    for (int i = 0; i < 8; ++i) {
        int gi = i0 + ty * 8 + i;
        int gj = j0 + tx * 4;
        if (gi < CIRC && gj < DIS) {
            *(float4*)(outp + (size_t)gi * DIS + gj) =
                make_float4(accv[i][0], accv[i][1], accv[i][2], accv[i][3]);
        }
    }
}

extern "C" void kernel_launch(void* const* d_in, const int* in_sizes, int n_in,
                              void* d_out, int out_size, void* d_ws, size_t ws_size,
                              hipStream_t stream) {
    const float* A    = (const float*)d_in[0];
    const float* circ = (const float*)d_in[1];
    const float* dis  = (const float*)d_in[2];
    const float* reCD = (const float*)d_in[3];
    float* ws  = (float*)d_ws;
    float* dc  = ws;                 // 10000 (becomes inv_c)
    float* dd  = ws + 10000;         // 4000  (becomes inv_d)
    float* Bc  = ws + 14000;         // 640000: inv_c * lc
    float* Bd  = ws + 654000;        // 256000: inv_d * ld
    float* gA  = ws + 910000;        // 640000: raw A@Bd   (contiguous with gB)
    float* gB  = ws + 1550000;       // 256000: raw A^T@Bc
    float* acc = ws + 1806000;       // 896000
    float* out = (float*)d_out;

    hipMemsetAsync(dd, 0, DIS * sizeof(float), stream);
    rowsum_kernel<<<2500, 256, 0, stream>>>(A, dc);
    colsum_kernel<<<dim3(16, 40), 256, 0, stream>>>(A, dd);
    inv_kernel<<<55, 256, 0, stream>>>(dc, dd);
    init_kernel<<<3500, 256, 0, stream>>>(circ, dis, dc, dd, Bc, Bd, acc);

    for (int layer = 0; layer < 3; ++layer) {
        hipMemsetAsync(gA, 0, (size_t)(CIRC + DIS) * LAT * sizeof(float), stream);
        // new_c raw: M=10000, K=4000, split-K 8 (KC=500, mult of 4)
        gemm_tn<false><<<dim3(79, 8), 256, 0, stream>>>(A, Bd, gA, CIRC, DIS, 500);
        // new_d raw: M=4000, K=10000, split-K 16 (KC=625, TRANS handles any klen)
        gemm_tn<true><<<dim3(32, 16), 256, 0, stream>>>(A, Bc, gB, DIS, CIRC, 625);
        update_kernel<<<3500, 256, 0, stream>>>(gA, gB, dc, dd, circ, dis, Bc, Bd, acc);
    }

    hipMemcpyAsync(out, acc, (size_t)(CIRC + DIS) * LAT * sizeof(float),
                   hipMemcpyDeviceToDevice, stream);
    predict_kernel<<<dim3(79, 63), 256, 0, stream>>>(acc, reCD, out + (size_t)(CIRC + DIS) * LAT);
}

// Round 2
// 752.450 us; speedup vs baseline: 1.5493x; 1.5493x over previous
//
#include <hip/hip_runtime.h>

#define CIRC 10000
#define DIS  4000
#define LAT  64
#define EPSF 1e-8f
#define KCP  10016   // CIRC padded to multiple of 32 (K of the transposed GEMM)

typedef __bf16 bf16x8 __attribute__((ext_vector_type(8)));
typedef __bf16 bf16x4 __attribute__((ext_vector_type(4)));
typedef float  f32x4  __attribute__((ext_vector_type(4)));

// ================= new bf16/MFMA path =================

// A fp32 -> Abf bf16, fused row sums
__global__ __launch_bounds__(256) void split_kernel(const float* __restrict__ A,
                                                    __bf16* __restrict__ Abf,
                                                    float* __restrict__ dc) {
    int wid = threadIdx.x >> 6, lane = threadIdx.x & 63;
    int r = blockIdx.x * 4 + wid;
    if (r >= CIRC) return;
    const float4* row = (const float4*)(A + (size_t)r * DIS);
    float s = 0.f;
    for (int c4 = lane; c4 < DIS / 4; c4 += 64) {
        float4 v = row[c4];
        s += v.x + v.y + v.z + v.w;
        bf16x4 h = {(__bf16)v.x, (__bf16)v.y, (__bf16)v.z, (__bf16)v.w};
        *(bf16x4*)(Abf + (size_t)r * DIS + c4 * 4) = h;
    }
    #pragma unroll
    for (int o = 32; o; o >>= 1) s += __shfl_down(s, o);
    if (lane == 0) dc[r] = s;
}

__global__ __launch_bounds__(256) void colsum_bf16(const __bf16* __restrict__ Abf,
                                                   float* __restrict__ dd) {
    int c = blockIdx.x * 256 + threadIdx.x;
    if (c >= DIS) return;
    int r0 = blockIdx.y * 250;
    float s = 0.f;
    for (int r = r0; r < r0 + 250; ++r) s += (float)Abf[(size_t)r * DIS + c];
    atomicAdd(&dd[c], s);
}

__global__ __launch_bounds__(256) void inv_kernel(float* __restrict__ dc, float* __restrict__ dd) {
    int i = blockIdx.x * 256 + threadIdx.x;
    if (i < CIRC) {
        float v = dc[i];
        dc[i] = (v > 0.f) ? rsqrtf(fmaxf(v, EPSF)) : 0.f;
    } else if (i < CIRC + DIS) {
        int j = i - CIRC;
        float v = dd[j];
        dd[j] = (v > 0.f) ? rsqrtf(fmaxf(v, EPSF)) : 0.f;
    }
}

// Abf (CIRC x DIS) -> AT (DIS x KCP), zero-padded cols [CIRC, KCP)
__global__ __launch_bounds__(256) void transpose_kernel(const __bf16* __restrict__ Abf,
                                                        __bf16* __restrict__ AT) {
    __shared__ __bf16 tile[64][65];
    const int t = threadIdx.x;
    const int c0 = blockIdx.x * 64;   // DIS dim
    const int r0 = blockIdx.y * 64;   // CIRC dim
    {
        int i = t >> 2, j0 = (t & 3) * 16;
        int r = r0 + i;
        bf16x8 v0 = {}, v1 = {};
        if (r < CIRC && c0 + j0 < DIS) {
            v0 = *(const bf16x8*)(Abf + (size_t)r * DIS + c0 + j0);
            v1 = *(const bf16x8*)(Abf + (size_t)r * DIS + c0 + j0 + 8);
        }
        #pragma unroll
        for (int e = 0; e < 8; ++e) { tile[i][j0 + e] = v0[e]; tile[i][j0 + 8 + e] = v1[e]; }
    }
    __syncthreads();
    {
        int c = c0 + (t >> 2);
        int rr = r0 + (t & 3) * 16;
        if (c < DIS && rr < KCP) {
            bf16x8 w0, w1;
            #pragma unroll
            for (int e = 0; e < 8; ++e) {
                w0[e] = tile[(t & 3) * 16 + e][t >> 2];
                w1[e] = tile[(t & 3) * 16 + 8 + e][t >> 2];
            }
            *(bf16x8*)(AT + (size_t)c * KCP + rr) = w0;
            *(bf16x8*)(AT + (size_t)c * KCP + rr + 8) = w1;
        }
    }
}

// BcT[j][i] = bf16(inv_c[i]*circ[i][j]) (64 x KCP, pad zeroed); BdT (64 x DIS); acc = 0
__global__ __launch_bounds__(256) void init_bf(const float* __restrict__ circ,
                                               const float* __restrict__ dis,
                                               const float* __restrict__ inv_c,
                                               const float* __restrict__ inv_d,
                                               __bf16* __restrict__ BcT, __bf16* __restrict__ BdT,
                                               float* __restrict__ acc) {
    int wid = threadIdx.x >> 6, lane = threadIdx.x & 63;
    int r = blockIdx.x * 4 + wid;
    if (r < CIRC) {
        float v = inv_c[r] * circ[(size_t)r * LAT + lane];
        BcT[(size_t)lane * KCP + r] = (__bf16)v;
        acc[(size_t)r * LAT + lane] = 0.f;
    } else if (r < CIRC + DIS) {
        int c = r - CIRC;
        float v = inv_d[c] * dis[(size_t)c * LAT + lane];
        BdT[(size_t)lane * DIS + c] = (__bf16)v;
        acc[(size_t)r * LAT + lane] = 0.f;
    } else if (r < CIRC + DIS + (KCP - CIRC)) {
        BcT[(size_t)lane * KCP + CIRC + (r - CIRC - DIS)] = (__bf16)0.0f;
    }
}

// C (M x 64) += Aop(M x K) @ BT(64 x K)^T. No LDS: direct-to-VGPR fragments.
// 256 thr = 4 waves; BM=128 (32 rows/wave); split-K over blockIdx.y, f32 atomics.
__global__ __launch_bounds__(256) void gemm_bf16(const __bf16* __restrict__ Aop, int ldA,
                                                 const __bf16* __restrict__ BT, int ldB,
                                                 float* __restrict__ C, int M, int K, int KC) {
    const int t = threadIdx.x;
    const int lane = t & 63, wave = t >> 6;
    const int l15 = lane & 15, lg = lane >> 4;
    const int m0 = blockIdx.x * 128 + wave * 32;
    const int kbeg = blockIdx.y * KC;
    int kend = kbeg + KC; if (kend > K) kend = K;

    const __bf16* pa = Aop + (size_t)(m0 + l15) * ldA + kbeg + lg * 8;
    const __bf16* pb = BT + (size_t)l15 * ldB + kbeg + lg * 8;
    const size_t a16 = (size_t)16 * ldA;
    const size_t b16 = (size_t)16 * ldB;

    f32x4 acc00 = {}, acc01 = {}, acc02 = {}, acc03 = {};
    f32x4 acc10 = {}, acc11 = {}, acc12 = {}, acc13 = {};

    #pragma unroll 2
    for (int k0 = kbeg; k0 < kend; k0 += 32) {
        bf16x8 a0 = *(const bf16x8*)(pa);
        bf16x8 a1 = *(const bf16x8*)(pa + a16);
        bf16x8 b0 = *(const bf16x8*)(pb);
        bf16x8 b1 = *(const bf16x8*)(pb + b16);
        bf16x8 b2 = *(const bf16x8*)(pb + 2 * b16);
        bf16x8 b3 = *(const bf16x8*)(pb + 3 * b16);
        acc00 = __builtin_amdgcn_mfma_f32_16x16x32_bf16(a0, b0, acc00, 0, 0, 0);
        acc01 = __builtin_amdgcn_mfma_f32_16x16x32_bf16(a0, b1, acc01, 0, 0, 0);
        acc02 = __builtin_amdgcn_mfma_f32_16x16x32_bf16(a0, b2, acc02, 0, 0, 0);
        acc03 = __builtin_amdgcn_mfma_f32_16x16x32_bf16(a0, b3, acc03, 0, 0, 0);
        acc10 = __builtin_amdgcn_mfma_f32_16x16x32_bf16(a1, b0, acc10, 0, 0, 0);
        acc11 = __builtin_amdgcn_mfma_f32_16x16x32_bf16(a1, b1, acc11, 0, 0, 0);
        acc12 = __builtin_amdgcn_mfma_f32_16x16x32_bf16(a1, b2, acc12, 0, 0, 0);
        acc13 = __builtin_amdgcn_mfma_f32_16x16x32_bf16(a1, b3, acc13, 0, 0, 0);
        pa += 32; pb += 32;
    }

    // D: row = (lane>>4)*4 + q (within 16-tile), col = lane&15
    f32x4* accs[2][4] = {{&acc00, &acc01, &acc02, &acc03}, {&acc10, &acc11, &acc12, &acc13}};
    #pragma unroll
    for (int wm = 0; wm < 2; ++wm) {
        #pragma unroll
        for (int q = 0; q < 4; ++q) {
            int m = m0 + wm * 16 + lg * 4 + q;
            if (m < M) {
                #pragma unroll
                for (int nt = 0; nt < 4; ++nt)
                    atomicAdd(&C[(size_t)m * LAT + nt * 16 + l15], (*accs[wm][nt])[q]);
            }
        }
    }
}

// cosine weight + accumulate + write next-layer bf16 transposed operands
__global__ __launch_bounds__(256) void update_bf(const float* __restrict__ gA,
                                                 const float* __restrict__ gB,
                                                 const float* __restrict__ inv_c,
                                                 const float* __restrict__ inv_d,
                                                 const float* __restrict__ circ,
                                                 const float* __restrict__ dis,
                                                 __bf16* __restrict__ BcT, __bf16* __restrict__ BdT,
                                                 float* __restrict__ acc) {
    int wid = threadIdx.x >> 6, lane = threadIdx.x & 63;
    int r = blockIdx.x * 4 + wid;
    if (r >= CIRC + DIS) return;
    float raw, ego, scale;
    if (r < CIRC) {
        scale = inv_c[r];
        raw = scale * gA[(size_t)r * LAT + lane];
        ego = circ[(size_t)r * LAT + lane];
    } else {
        int c = r - CIRC;
        scale = inv_d[c];
        raw = scale * gB[(size_t)c * LAT + lane];
        ego = dis[(size_t)c * LAT + lane];
    }
    float dot = raw * ego, n1 = raw * raw, n2 = ego * ego;
    #pragma unroll
    for (int o = 32; o; o >>= 1) {
        dot += __shfl_down(dot, o);
        n1  += __shfl_down(n1, o);
        n2  += __shfl_down(n2, o);
    }
    dot = __shfl(dot, 0); n1 = __shfl(n1, 0); n2 = __shfl(n2, 0);
    float w = dot / (fmaxf(sqrtf(n1), EPSF) * fmaxf(sqrtf(n2), EPSF));
    float val = w * raw;
    acc[(size_t)r * LAT + lane] += val;
    if (r < CIRC) BcT[(size_t)lane * KCP + r] = (__bf16)(scale * val);
    else          BdT[(size_t)lane * DIS + (r - CIRC)] = (__bf16)(scale * val);
}

// predict = (circ_all * diag) @ dis_all^T (fp32)
__global__ __launch_bounds__(256) void predict_kernel(const float* __restrict__ acc,
                                                      const float* __restrict__ reCD,
                                                      float* __restrict__ outp) {
    __shared__ float XsT[64][132];
    __shared__ float YsT[64][68];
    __shared__ float dl[64];
    const int t = threadIdx.x;
    const int i0 = blockIdx.x * 128;
    const int j0 = blockIdx.y * 64;
    const float* circ_all = acc;
    const float* dis_all  = acc + (size_t)CIRC * LAT;
    if (t < 64) dl[t] = reCD[t * 65];
    __syncthreads();
    #pragma unroll
    for (int p = 0; p < 8; ++p) {
        int q  = t + (p << 8);
        int ii = q >> 4;
        int lv = (q & 15) << 2;
        float4 v = make_float4(0.f, 0.f, 0.f, 0.f);
        if (i0 + ii < CIRC) v = *(const float4*)(circ_all + (size_t)(i0 + ii) * LAT + lv);
        XsT[lv + 0][ii] = v.x * dl[lv + 0];
        XsT[lv + 1][ii] = v.y * dl[lv + 1];
        XsT[lv + 2][ii] = v.z * dl[lv + 2];
        XsT[lv + 3][ii] = v.w * dl[lv + 3];
        if (p < 4) {
            int jj = ii;
            float4 u = make_float4(0.f, 0.f, 0.f, 0.f);
            if (j0 + jj < DIS) u = *(const float4*)(dis_all + (size_t)(j0 + jj) * LAT + lv);
            YsT[lv + 0][jj] = u.x;
            YsT[lv + 1][jj] = u.y;
            YsT[lv + 2][jj] = u.z;
            YsT[lv + 3][jj] = u.w;
        }
    }
    __syncthreads();
    const int tx = t & 15, ty = t >> 4;
    float accv[8][4];
    #pragma unroll
    for (int i = 0; i < 8; ++i)
        #pragma unroll
        for (int j = 0; j < 4; ++j) accv[i][j] = 0.f;
    #pragma unroll 8
    for (int l = 0; l < 64; ++l) {
        float4 a0 = *(float4*)&XsT[l][ty * 8];
        float4 a1 = *(float4*)&XsT[l][ty * 8 + 4];
        float4 bv = *(float4*)&YsT[l][tx * 4];
        float af[8] = {a0.x, a0.y, a0.z, a0.w, a1.x, a1.y, a1.z, a1.w};
        float bf[4] = {bv.x, bv.y, bv.z, bv.w};
        #pragma unroll
        for (int i = 0; i < 8; ++i)
            #pragma unroll
            for (int j = 0; j < 4; ++j) accv[i][j] = fmaf(af[i], bf[j], accv[i][j]);
    }
    #pragma unroll
    for (int i = 0; i < 8; ++i) {
        int gi = i0 + ty * 8 + i;
        int gj = j0 + tx * 4;
        if (gi < CIRC && gj < DIS) {
            *(float4*)(outp + (size_t)gi * DIS + gj) =
                make_float4(accv[i][0], accv[i][1], accv[i][2], accv[i][3]);
        }
    }
}

// ================= fp32 fallback path (R1 kernels, used if ws too small) =================

__global__ __launch_bounds__(256) void rowsum_kernel(const float* __restrict__ A,
                                                     float* __restrict__ dc) {
    int wid = threadIdx.x >> 6, lane = threadIdx.x & 63;
    int r = blockIdx.x * 4 + wid;
    if (r >= CIRC) return;
    const float4* row = (const float4*)(A + (size_t)r * DIS);
    float s = 0.f;
    for (int c4 = lane; c4 < DIS / 4; c4 += 64) {
        float4 v = row[c4];
        s += v.x + v.y + v.z + v.w;
    }
    #pragma unroll
    for (int o = 32; o; o >>= 1) s += __shfl_down(s, o);
    if (lane == 0) dc[r] = s;
}

__global__ __launch_bounds__(256) void colsum_f32(const float* __restrict__ A,
                                                  float* __restrict__ dd) {
    int c = blockIdx.x * 256 + threadIdx.x;
    if (c >= DIS) return;
    int r0 = blockIdx.y * 250;
    float s = 0.f;
    for (int r = r0; r < r0 + 250; ++r) s += A[(size_t)r * DIS + c];
    atomicAdd(&dd[c], s);
}

__global__ __launch_bounds__(256) void init_f32(const float* __restrict__ circ,
                                                const float* __restrict__ dis,
                                                const float* __restrict__ inv_c,
                                                const float* __restrict__ inv_d,
                                                float* __restrict__ Bc, float* __restrict__ Bd,
                                                float* __restrict__ acc) {
    int idx = blockIdx.x * 256 + threadIdx.x;
    if (idx >= (CIRC + DIS) * LAT) return;
    int r = idx >> 6;
    if (r < CIRC) Bc[idx] = inv_c[r] * circ[idx];
    else { int cidx = idx - CIRC * LAT; Bd[cidx] = inv_d[r - CIRC] * dis[cidx]; }
    acc[idx] = 0.f;
}

template <bool TRANS>
__global__ __launch_bounds__(256) void gemm_tn(const float* __restrict__ Ag,
                                               const float* __restrict__ B,
                                               float* __restrict__ C,
                                               int M, int K, int KC) {
    __shared__ float As[16][132];
    __shared__ float Bs[16][64];
    const int t  = threadIdx.x;
    const int tx = t & 15, ty = t >> 4;
    const int m0 = blockIdx.x * 128;
    const int kbeg = blockIdx.y * KC;
    const int kend = (kbeg + KC < K) ? (kbeg + KC) : K;
    float acc[8][4];
    #pragma unroll
    for (int i = 0; i < 8; ++i)
        #pragma unroll
        for (int j = 0; j < 4; ++j) acc[i][j] = 0.f;
    for (int k0 = kbeg; k0 < kend; k0 += 16) {
        const int klen = kend - k0;
        if (TRANS) {
            #pragma unroll
            for (int p = 0; p < 2; ++p) {
                int q  = t + (p << 8);
                int kk = q >> 5;
                int mv = (q & 31) << 2;
                float4 v = make_float4(0.f, 0.f, 0.f, 0.f);
                int m = m0 + mv;
                if (kk < klen && m < M)
                    v = *(const float4*)(Ag + (size_t)(k0 + kk) * DIS + m);
                *(float4*)&As[kk][mv] = v;
            }
        } else {
            #pragma unroll
            for (int p = 0; p < 2; ++p) {
                int q  = t + (p << 8);
                int mm = q >> 2;
                int kv = (q & 3) << 2;
                float4 v = make_float4(0.f, 0.f, 0.f, 0.f);
                int m = m0 + mm;
                if (m < M && kv < klen)
                    v = *(const float4*)(Ag + (size_t)m * DIS + k0 + kv);
                As[kv + 0][mm] = v.x;
                As[kv + 1][mm] = v.y;
                As[kv + 2][mm] = v.z;
                As[kv + 3][mm] = v.w;
            }
        }
        {
            int kk = t >> 4, jv = (t & 15) << 2;
            float4 v = make_float4(0.f, 0.f, 0.f, 0.f);
            if (kk < klen) v = *(const float4*)(B + (size_t)(k0 + kk) * LAT + jv);
            *(float4*)&Bs[kk][jv] = v;
        }
        __syncthreads();
        #pragma unroll
        for (int kk = 0; kk < 16; ++kk) {
            float4 a0 = *(float4*)&As[kk][ty * 8];
            float4 a1 = *(float4*)&As[kk][ty * 8 + 4];
            float4 bv = *(float4*)&Bs[kk][tx * 4];
            float af[8] = {a0.x, a0.y, a0.z, a0.w, a1.x, a1.y, a1.z, a1.w};
            float bf[4] = {bv.x, bv.y, bv.z, bv.w};
            #pragma unroll
            for (int i = 0; i < 8; ++i)
                #pragma unroll
                for (int j = 0; j < 4; ++j) acc[i][j] = fmaf(af[i], bf[j], acc[i][j]);
        }
        __syncthreads();
    }
    #pragma unroll
    for (int i = 0; i < 8; ++i) {
        int m = m0 + ty * 8 + i;
        if (m < M) {
            #pragma unroll
            for (int j = 0; j < 4; ++j)
                atomicAdd(&C[(size_t)m * LAT + tx * 4 + j], acc[i][j]);
        }
    }
}

__global__ __launch_bounds__(256) void update_f32(const float* __restrict__ gA,
                                                  const float* __restrict__ gB,
                                                  const float* __restrict__ inv_c,
                                                  const float* __restrict__ inv_d,
                                                  const float* __restrict__ circ,
                                                  const float* __restrict__ dis,
                                                  float* __restrict__ Bc, float* __restrict__ Bd,
                                                  float* __restrict__ acc) {
    int wid = threadIdx.x >> 6, lane = threadIdx.x & 63;
    int r = blockIdx.x * 4 + wid;
    if (r >= CIRC + DIS) return;
    float raw, ego, scale;
    if (r < CIRC) {
        scale = inv_c[r];
        raw = scale * gA[(size_t)r * LAT + lane];
        ego = circ[(size_t)r * LAT + lane];
    } else {
        int c = r - CIRC;
        scale = inv_d[c];
        raw = scale * gB[(size_t)c * LAT + lane];
        ego = dis[(size_t)c * LAT + lane];
    }
    float dot = raw * ego, n1 = raw * raw, n2 = ego * ego;
    #pragma unroll
    for (int o = 32; o; o >>= 1) {
        dot += __shfl_down(dot, o);
        n1  += __shfl_down(n1, o);
        n2  += __shfl_down(n2, o);
    }
    dot = __shfl(dot, 0); n1 = __shfl(n1, 0); n2 = __shfl(n2, 0);
    float w = dot / (fmaxf(sqrtf(n1), EPSF) * fmaxf(sqrtf(n2), EPSF));
    float val = w * raw;
    acc[(size_t)r * LAT + lane] += val;
    if (r < CIRC) Bc[(size_t)r * LAT + lane] = scale * val;
    else          Bd[(size_t)(r - CIRC) * LAT + lane] = scale * val;
}

// ================= launcher =================

extern "C" void kernel_launch(void* const* d_in, const int* in_sizes, int n_in,
                              void* d_out, int out_size, void* d_ws, size_t ws_size,
                              hipStream_t stream) {
    const float* A    = (const float*)d_in[0];
    const float* circ = (const float*)d_in[1];
    const float* dis  = (const float*)d_in[2];
    const float* reCD = (const float*)d_in[3];
    float* out = (float*)d_out;
    char* w = (char*)d_ws;

    const size_t NEED = 172ull * 1024 * 1024;  // 171.08 MB actually used (incl. overrun slack)
    if (ws_size >= NEED) {
        float*  dc   = (float*) (w + 0);          // 40,000 B
        float*  dd   = (float*) (w + 40000);      // 16,000 B
        float*  gA   = (float*) (w + 64000);      // 2,560,000 B
        float*  gB   = (float*) (w + 2624000);    // 1,024,000 B
        float*  acc  = (float*) (w + 3648000);    // 3,584,000 B
        __bf16* BdT  = (__bf16*)(w + 7232000);    // 512,000 B   (64 x DIS)
        __bf16* BcT  = (__bf16*)(w + 7744000);    // 1,282,048 B (64 x KCP)
        __bf16* Abf  = (__bf16*)(w + 9026560);    // 80,000,000 B (CIRC x DIS)
        __bf16* ATbf = (__bf16*)(w + 89026560);   // 80,128,000 B (DIS x KCP)

        hipMemsetAsync(dd, 0, DIS * sizeof(float), stream);
        split_kernel<<<2500, 256, 0, stream>>>(A, Abf, dc);
        colsum_bf16<<<dim3(16, 40), 256, 0, stream>>>(Abf, dd);
        transpose_kernel<<<dim3(63, 157), 256, 0, stream>>>(Abf, ATbf);
        inv_kernel<<<55, 256, 0, stream>>>(dc, dd);
        init_bf<<<3504, 256, 0, stream>>>(circ, dis, dc, dd, BcT, BdT, acc);

        for (int layer = 0; layer < 3; ++layer) {
            hipMemsetAsync(gA, 0, 3584000, stream);  // gA + gB contiguous
            gemm_bf16<<<dim3(79, 16), 256, 0, stream>>>(Abf, DIS, BdT, DIS, gA, CIRC, DIS, 256);
            gemm_bf16<<<dim3(32, 40), 256, 0, stream>>>(ATbf, KCP, BcT, KCP, gB, DIS, KCP, 256);
            update_bf<<<3500, 256, 0, stream>>>(gA, gB, dc, dd, circ, dis, BcT, BdT, acc);
        }

        hipMemcpyAsync(out, acc, (size_t)(CIRC + DIS) * LAT * sizeof(float),
                       hipMemcpyDeviceToDevice, stream);
        predict_kernel<<<dim3(79, 63), 256, 0, stream>>>(acc, reCD, out + (size_t)(CIRC + DIS) * LAT);
    } else {
        float* ws  = (float*)d_ws;
        float* dc  = ws;
        float* dd  = ws + 10000;
        float* Bc  = ws + 14000;
        float* Bd  = ws + 654000;
        float* gA  = ws + 910000;
        float* gB  = ws + 1550000;
        float* acc = ws + 1806000;

        hipMemsetAsync(dd, 0, DIS * sizeof(float), stream);
        rowsum_kernel<<<2500, 256, 0, stream>>>(A, dc);
        colsum_f32<<<dim3(16, 40), 256, 0, stream>>>(A, dd);
        inv_kernel<<<55, 256, 0, stream>>>(dc, dd);
        init_f32<<<3500, 256, 0, stream>>>(circ, dis, dc, dd, Bc, Bd, acc);

        for (int layer = 0; layer < 3; ++layer) {
            hipMemsetAsync(gA, 0, (size_t)(CIRC + DIS) * LAT * sizeof(float), stream);
            gemm_tn<false><<<dim3(79, 8), 256, 0, stream>>>(A, Bd, gA, CIRC, DIS, 500);
            gemm_tn<true><<<dim3(32, 16), 256, 0, stream>>>(A, Bc, gB, DIS, CIRC, 625);
            update_f32<<<3500, 256, 0, stream>>>(gA, gB, dc, dd, circ, dis, Bc, Bd, acc);
        }

        hipMemcpyAsync(out, acc, (size_t)(CIRC + DIS) * LAT * sizeof(float),
                       hipMemcpyDeviceToDevice, stream);
        predict_kernel<<<dim3(79, 63), 256, 0, stream>>>(acc, reCD, out + (size_t)(CIRC + DIS) * LAT);
    }
}

// Round 3
// 662.133 us; speedup vs baseline: 1.7607x; 1.1364x over previous
//
#include <hip/hip_runtime.h>

#define CIRC 10000
#define DIS  4000
#define LAT  64
#define EPSF 1e-8f
#define S1   16     // gemm1 split-K count (KC1=256)
#define KC1  256
#define S2   40     // gemm2 split-K count (KC2=256)
#define KC2  256

typedef __bf16 bf16x8 __attribute__((ext_vector_type(8)));
typedef __bf16 bf16x4 __attribute__((ext_vector_type(4)));
typedef float  f32x4  __attribute__((ext_vector_type(4)));

// ================= bf16/MFMA path =================

// A fp32 -> Abf bf16, fused row sums
__global__ __launch_bounds__(256) void split_kernel(const float* __restrict__ A,
                                                    __bf16* __restrict__ Abf,
                                                    float* __restrict__ dc) {
    int wid = threadIdx.x >> 6, lane = threadIdx.x & 63;
    int r = blockIdx.x * 4 + wid;
    if (r >= CIRC) return;
    const float4* row = (const float4*)(A + (size_t)r * DIS);
    float s = 0.f;
    for (int c4 = lane; c4 < DIS / 4; c4 += 64) {
        float4 v = row[c4];
        s += v.x + v.y + v.z + v.w;
        bf16x4 h = {(__bf16)v.x, (__bf16)v.y, (__bf16)v.z, (__bf16)v.w};
        *(bf16x4*)(Abf + (size_t)r * DIS + c4 * 4) = h;
    }
    #pragma unroll
    for (int o = 32; o; o >>= 1) s += __shfl_down(s, o);
    if (lane == 0) dc[r] = s;
}

__global__ __launch_bounds__(256) void colsum_bf16(const __bf16* __restrict__ Abf,
                                                   float* __restrict__ dd) {
    int c = blockIdx.x * 256 + threadIdx.x;
    if (c >= DIS) return;
    int r0 = blockIdx.y * 250;
    float s = 0.f;
    for (int r = r0; r < r0 + 250; ++r) s += (float)Abf[(size_t)r * DIS + c];
    atomicAdd(&dd[c], s);
}

__global__ __launch_bounds__(256) void inv_kernel(float* __restrict__ dc, float* __restrict__ dd) {
    int i = blockIdx.x * 256 + threadIdx.x;
    if (i < CIRC) {
        float v = dc[i];
        dc[i] = (v > 0.f) ? rsqrtf(fmaxf(v, EPSF)) : 0.f;
    } else if (i < CIRC + DIS) {
        int j = i - CIRC;
        float v = dd[j];
        dd[j] = (v > 0.f) ? rsqrtf(fmaxf(v, EPSF)) : 0.f;
    }
}

// Bc[k][j] = bf16(inv_c[k]*circ[k][j]) row-major; Bd likewise; acc = 0. Coalesced.
__global__ __launch_bounds__(256) void init2(const float* __restrict__ circ,
                                             const float* __restrict__ dis,
                                             const float* __restrict__ inv_c,
                                             const float* __restrict__ inv_d,
                                             __bf16* __restrict__ Bc, __bf16* __restrict__ Bd,
                                             float* __restrict__ acc) {
    int wid = threadIdx.x >> 6, lane = threadIdx.x & 63;
    int r = blockIdx.x * 4 + wid;
    if (r >= CIRC + DIS) return;
    if (r < CIRC) {
        Bc[(size_t)r * LAT + lane] = (__bf16)(inv_c[r] * circ[(size_t)r * LAT + lane]);
    } else {
        int c = r - CIRC;
        Bd[(size_t)c * LAT + lane] = (__bf16)(inv_d[c] * dis[(size_t)c * LAT + lane]);
    }
    acc[(size_t)r * LAT + lane] = 0.f;
}

// ---- gemm1: P1[s] = Abf(CIRC x DIS, direct) @ Bd(DIS x 64)^T-staged-in-LDS ----
__global__ __launch_bounds__(256) void gemm1_bf16(const __bf16* __restrict__ Abf,
                                                  const __bf16* __restrict__ Bd,
                                                  float* __restrict__ P1) {
    __shared__ __bf16 Bs[64][136];   // [j][k-chunk 128], row = 272 B = 17*16
    const int t = threadIdx.x;
    const int lane = t & 63, wave = t >> 6;
    const int l15 = lane & 15, lg = lane >> 4;
    const int m0 = blockIdx.x * 128 + wave * 32;
    const int kbeg = blockIdx.y * KC1;
    const int kend = (kbeg + KC1 < DIS) ? (kbeg + KC1) : DIS;

    const __bf16* pa = Abf + (size_t)(m0 + l15) * DIS + kbeg + lg * 8;
    const size_t a16 = (size_t)16 * DIS;

    f32x4 acc00 = {}, acc01 = {}, acc02 = {}, acc03 = {};
    f32x4 acc10 = {}, acc11 = {}, acc12 = {}, acc13 = {};

    for (int kc = kbeg; kc < kend; kc += 128) {
        #pragma unroll
        for (int p = 0; p < 4; ++p) {
            int q  = t + (p << 8);        // 1024 slots: 128 k x 8 j-groups
            int kk = q >> 3;
            int jj = (q & 7) << 3;
            bf16x8 v = {};
            if (kc + kk < DIS) v = *(const bf16x8*)(Bd + (size_t)(kc + kk) * LAT + jj);
            #pragma unroll
            for (int e = 0; e < 8; ++e) Bs[jj + e][kk] = v[e];
        }
        __syncthreads();
        const __bf16* pA = pa + (kc - kbeg);
        #pragma unroll
        for (int s = 0; s < 4; ++s) {
            bf16x8 a0 = *(const bf16x8*)(pA + s * 32);
            bf16x8 a1 = *(const bf16x8*)(pA + a16 + s * 32);
            bf16x8 b0 = *(const bf16x8*)(&Bs[l15     ][s * 32 + lg * 8]);
            bf16x8 b1 = *(const bf16x8*)(&Bs[l15 + 16][s * 32 + lg * 8]);
            bf16x8 b2 = *(const bf16x8*)(&Bs[l15 + 32][s * 32 + lg * 8]);
            bf16x8 b3 = *(const bf16x8*)(&Bs[l15 + 48][s * 32 + lg * 8]);
            acc00 = __builtin_amdgcn_mfma_f32_16x16x32_bf16(a0, b0, acc00, 0, 0, 0);
            acc01 = __builtin_amdgcn_mfma_f32_16x16x32_bf16(a0, b1, acc01, 0, 0, 0);
            acc02 = __builtin_amdgcn_mfma_f32_16x16x32_bf16(a0, b2, acc02, 0, 0, 0);
            acc03 = __builtin_amdgcn_mfma_f32_16x16x32_bf16(a0, b3, acc03, 0, 0, 0);
            acc10 = __builtin_amdgcn_mfma_f32_16x16x32_bf16(a1, b0, acc10, 0, 0, 0);
            acc11 = __builtin_amdgcn_mfma_f32_16x16x32_bf16(a1, b1, acc11, 0, 0, 0);
            acc12 = __builtin_amdgcn_mfma_f32_16x16x32_bf16(a1, b2, acc12, 0, 0, 0);
            acc13 = __builtin_amdgcn_mfma_f32_16x16x32_bf16(a1, b3, acc13, 0, 0, 0);
        }
        __syncthreads();
    }
    float* C = P1 + (size_t)blockIdx.y * CIRC * LAT;
    f32x4* accs[2][4] = {{&acc00, &acc01, &acc02, &acc03}, {&acc10, &acc11, &acc12, &acc13}};
    #pragma unroll
    for (int wm = 0; wm < 2; ++wm)
        #pragma unroll
        for (int q = 0; q < 4; ++q) {
            int m = m0 + wm * 16 + lg * 4 + q;
            if (m < CIRC) {
                #pragma unroll
                for (int nt = 0; nt < 4; ++nt)
                    C[(size_t)m * LAT + nt * 16 + l15] = (*accs[wm][nt])[q];
            }
        }
}

// ---- gemm2: P2[s] = A^T(DIS x CIRC, LDS-transpose-staged) @ Bc(CIRC x 64)^T-staged ----
__global__ __launch_bounds__(256) void gemm2_bf16(const __bf16* __restrict__ Abf,
                                                  const __bf16* __restrict__ Bc,
                                                  float* __restrict__ P2) {
    __shared__ __bf16 As[128][72];   // [c][k-chunk 64], row = 144 B = 9*16
    __shared__ __bf16 Bs[64][72];
    const int t = threadIdx.x;
    const int lane = t & 63, wave = t >> 6;
    const int l15 = lane & 15, lg = lane >> 4;
    const int c0 = blockIdx.x * 128;
    const int cw = c0 + wave * 32;
    const int kbeg = blockIdx.y * KC2;
    const int kend = (kbeg + KC2 < CIRC) ? (kbeg + KC2) : CIRC;

    f32x4 acc00 = {}, acc01 = {}, acc02 = {}, acc03 = {};
    f32x4 acc10 = {}, acc11 = {}, acc12 = {}, acc13 = {};

    for (int kc = kbeg; kc < kend; kc += 64) {
        #pragma unroll
        for (int p = 0; p < 4; ++p) {
            int q  = t + (p << 8);        // 1024 slots: 64 k x 16 c-groups
            int kk = q >> 4;
            int cc = (q & 15) << 3;
            bf16x8 v = {};
            if (kc + kk < CIRC && c0 + cc < DIS)
                v = *(const bf16x8*)(Abf + (size_t)(kc + kk) * DIS + c0 + cc);
            #pragma unroll
            for (int e = 0; e < 8; ++e) As[cc + e][kk] = v[e];
        }
        #pragma unroll
        for (int p = 0; p < 2; ++p) {
            int q  = t + (p << 8);        // 512 slots: 64 k x 8 j-groups
            int kk = q >> 3;
            int jj = (q & 7) << 3;
            bf16x8 v = {};
            if (kc + kk < CIRC) v = *(const bf16x8*)(Bc + (size_t)(kc + kk) * LAT + jj);
            #pragma unroll
            for (int e = 0; e < 8; ++e) Bs[jj + e][kk] = v[e];
        }
        __syncthreads();
        #pragma unroll
        for (int s = 0; s < 2; ++s) {
            bf16x8 a0 = *(const bf16x8*)(&As[(wave * 32) + l15     ][s * 32 + lg * 8]);
            bf16x8 a1 = *(const bf16x8*)(&As[(wave * 32) + 16 + l15][s * 32 + lg * 8]);
            bf16x8 b0 = *(const bf16x8*)(&Bs[l15     ][s * 32 + lg * 8]);
            bf16x8 b1 = *(const bf16x8*)(&Bs[l15 + 16][s * 32 + lg * 8]);
            bf16x8 b2 = *(const bf16x8*)(&Bs[l15 + 32][s * 32 + lg * 8]);
            bf16x8 b3 = *(const bf16x8*)(&Bs[l15 + 48][s * 32 + lg * 8]);
            acc00 = __builtin_amdgcn_mfma_f32_16x16x32_bf16(a0, b0, acc00, 0, 0, 0);
            acc01 = __builtin_amdgcn_mfma_f32_16x16x32_bf16(a0, b1, acc01, 0, 0, 0);
            acc02 = __builtin_amdgcn_mfma_f32_16x16x32_bf16(a0, b2, acc02, 0, 0, 0);
            acc03 = __builtin_amdgcn_mfma_f32_16x16x32_bf16(a0, b3, acc03, 0, 0, 0);
            acc10 = __builtin_amdgcn_mfma_f32_16x16x32_bf16(a1, b0, acc10, 0, 0, 0);
            acc11 = __builtin_amdgcn_mfma_f32_16x16x32_bf16(a1, b1, acc11, 0, 0, 0);
            acc12 = __builtin_amdgcn_mfma_f32_16x16x32_bf16(a1, b2, acc12, 0, 0, 0);
            acc13 = __builtin_amdgcn_mfma_f32_16x16x32_bf16(a1, b3, acc13, 0, 0, 0);
        }
        __syncthreads();
    }
    float* C = P2 + (size_t)blockIdx.y * DIS * LAT;
    f32x4* accs[2][4] = {{&acc00, &acc01, &acc02, &acc03}, {&acc10, &acc11, &acc12, &acc13}};
    #pragma unroll
    for (int wm = 0; wm < 2; ++wm)
        #pragma unroll
        for (int q = 0; q < 4; ++q) {
            int m = cw + wm * 16 + lg * 4 + q;
            if (m < DIS) {
                #pragma unroll
                for (int nt = 0; nt < 4; ++nt)
                    C[(size_t)m * LAT + nt * 16 + l15] = (*accs[wm][nt])[q];
            }
        }
}

// reduce partials + cosine weight + accumulate + write next-layer bf16 row-major operands
__global__ __launch_bounds__(256) void update2(const float* __restrict__ P1,
                                               const float* __restrict__ P2,
                                               const float* __restrict__ inv_c,
                                               const float* __restrict__ inv_d,
                                               const float* __restrict__ circ,
                                               const float* __restrict__ dis,
                                               __bf16* __restrict__ Bc, __bf16* __restrict__ Bd,
                                               float* __restrict__ acc) {
    int wid = threadIdx.x >> 6, lane = threadIdx.x & 63;
    int r = blockIdx.x * 4 + wid;
    if (r >= CIRC + DIS) return;
    float raw, ego, scale;
    if (r < CIRC) {
        scale = inv_c[r];
        float s = 0.f;
        #pragma unroll
        for (int p = 0; p < S1; ++p) s += P1[(size_t)p * CIRC * LAT + (size_t)r * LAT + lane];
        raw = scale * s;
        ego = circ[(size_t)r * LAT + lane];
    } else {
        int c = r - CIRC;
        scale = inv_d[c];
        float s = 0.f;
        #pragma unroll
        for (int p = 0; p < S2; ++p) s += P2[(size_t)p * DIS * LAT + (size_t)c * LAT + lane];
        raw = scale * s;
        ego = dis[(size_t)c * LAT + lane];
    }
    float dot = raw * ego, n1 = raw * raw, n2 = ego * ego;
    #pragma unroll
    for (int o = 32; o; o >>= 1) {
        dot += __shfl_down(dot, o);
        n1  += __shfl_down(n1, o);
        n2  += __shfl_down(n2, o);
    }
    dot = __shfl(dot, 0); n1 = __shfl(n1, 0); n2 = __shfl(n2, 0);
    float w = dot / (fmaxf(sqrtf(n1), EPSF) * fmaxf(sqrtf(n2), EPSF));
    float val = w * raw;
    acc[(size_t)r * LAT + lane] += val;
    if (r < CIRC) Bc[(size_t)r * LAT + lane] = (__bf16)(scale * val);
    else          Bd[(size_t)(r - CIRC) * LAT + lane] = (__bf16)(scale * val);
}

// predict = (circ_all * diag) @ dis_all^T (fp32)
__global__ __launch_bounds__(256) void predict_kernel(const float* __restrict__ acc,
                                                      const float* __restrict__ reCD,
                                                      float* __restrict__ outp) {
    __shared__ float XsT[64][132];
    __shared__ float YsT[64][68];
    __shared__ float dl[64];
    const int t = threadIdx.x;
    const int i0 = blockIdx.x * 128;
    const int j0 = blockIdx.y * 64;
    const float* circ_all = acc;
    const float* dis_all  = acc + (size_t)CIRC * LAT;
    if (t < 64) dl[t] = reCD[t * 65];
    __syncthreads();
    #pragma unroll
    for (int p = 0; p < 8; ++p) {
        int q  = t + (p << 8);
        int ii = q >> 4;
        int lv = (q & 15) << 2;
        float4 v = make_float4(0.f, 0.f, 0.f, 0.f);
        if (i0 + ii < CIRC) v = *(const float4*)(circ_all + (size_t)(i0 + ii) * LAT + lv);
        XsT[lv + 0][ii] = v.x * dl[lv + 0];
        XsT[lv + 1][ii] = v.y * dl[lv + 1];
        XsT[lv + 2][ii] = v.z * dl[lv + 2];
        XsT[lv + 3][ii] = v.w * dl[lv + 3];
        if (p < 4) {
            int jj = ii;
            float4 u = make_float4(0.f, 0.f, 0.f, 0.f);
            if (j0 + jj < DIS) u = *(const float4*)(dis_all + (size_t)(j0 + jj) * LAT + lv);
            YsT[lv + 0][jj] = u.x;
            YsT[lv + 1][jj] = u.y;
            YsT[lv + 2][jj] = u.z;
            YsT[lv + 3][jj] = u.w;
        }
    }
    __syncthreads();
    const int tx = t & 15, ty = t >> 4;
    float accv[8][4];
    #pragma unroll
    for (int i = 0; i < 8; ++i)
        #pragma unroll
        for (int j = 0; j < 4; ++j) accv[i][j] = 0.f;
    #pragma unroll 8
    for (int l = 0; l < 64; ++l) {
        float4 a0 = *(float4*)&XsT[l][ty * 8];
        float4 a1 = *(float4*)&XsT[l][ty * 8 + 4];
        float4 bv = *(float4*)&YsT[l][tx * 4];
        float af[8] = {a0.x, a0.y, a0.z, a0.w, a1.x, a1.y, a1.z, a1.w};
        float bf[4] = {bv.x, bv.y, bv.z, bv.w};
        #pragma unroll
        for (int i = 0; i < 8; ++i)
            #pragma unroll
            for (int j = 0; j < 4; ++j) accv[i][j] = fmaf(af[i], bf[j], accv[i][j]);
    }
    #pragma unroll
    for (int i = 0; i < 8; ++i) {
        int gi = i0 + ty * 8 + i;
        int gj = j0 + tx * 4;
        if (gi < CIRC && gj < DIS) {
            *(float4*)(outp + (size_t)gi * DIS + gj) =
                make_float4(accv[i][0], accv[i][1], accv[i][2], accv[i][3]);
        }
    }
}

// ================= fp32 fallback path =================

__global__ __launch_bounds__(256) void rowsum_kernel(const float* __restrict__ A,
                                                     float* __restrict__ dc) {
    int wid = threadIdx.x >> 6, lane = threadIdx.x & 63;
    int r = blockIdx.x * 4 + wid;
    if (r >= CIRC) return;
    const float4* row = (const float4*)(A + (size_t)r * DIS);
    float s = 0.f;
    for (int c4 = lane; c4 < DIS / 4; c4 += 64) {
        float4 v = row[c4];
        s += v.x + v.y + v.z + v.w;
    }
    #pragma unroll
    for (int o = 32; o; o >>= 1) s += __shfl_down(s, o);
    if (lane == 0) dc[r] = s;
}

__global__ __launch_bounds__(256) void colsum_f32(const float* __restrict__ A,
                                                  float* __restrict__ dd) {
    int c = blockIdx.x * 256 + threadIdx.x;
    if (c >= DIS) return;
    int r0 = blockIdx.y * 250;
    float s = 0.f;
    for (int r = r0; r < r0 + 250; ++r) s += A[(size_t)r * DIS + c];
    atomicAdd(&dd[c], s);
}

__global__ __launch_bounds__(256) void init_f32(const float* __restrict__ circ,
                                                const float* __restrict__ dis,
                                                const float* __restrict__ inv_c,
                                                const float* __restrict__ inv_d,
                                                float* __restrict__ Bc, float* __restrict__ Bd,
                                                float* __restrict__ acc) {
    int idx = blockIdx.x * 256 + threadIdx.x;
    if (idx >= (CIRC + DIS) * LAT) return;
    int r = idx >> 6;
    if (r < CIRC) Bc[idx] = inv_c[r] * circ[idx];
    else { int cidx = idx - CIRC * LAT; Bd[cidx] = inv_d[r - CIRC] * dis[cidx]; }
    acc[idx] = 0.f;
}

template <bool TRANS>
__global__ __launch_bounds__(256) void gemm_tn(const float* __restrict__ Ag,
                                               const float* __restrict__ B,
                                               float* __restrict__ C,
                                               int M, int K, int KC) {
    __shared__ float As[16][132];
    __shared__ float Bs[16][64];
    const int t  = threadIdx.x;
    const int tx = t & 15, ty = t >> 4;
    const int m0 = blockIdx.x * 128;
    const int kbeg = blockIdx.y * KC;
    const int kend = (kbeg + KC < K) ? (kbeg + KC) : K;
    float acc[8][4];
    #pragma unroll
    for (int i = 0; i < 8; ++i)
        #pragma unroll
        for (int j = 0; j < 4; ++j) acc[i][j] = 0.f;
    for (int k0 = kbeg; k0 < kend; k0 += 16) {
        const int klen = kend - k0;
        if (TRANS) {
            #pragma unroll
            for (int p = 0; p < 2; ++p) {
                int q  = t + (p << 8);
                int kk = q >> 5;
                int mv = (q & 31) << 2;
                float4 v = make_float4(0.f, 0.f, 0.f, 0.f);
                int m = m0 + mv;
                if (kk < klen && m < M)
                    v = *(const float4*)(Ag + (size_t)(k0 + kk) * DIS + m);
                *(float4*)&As[kk][mv] = v;
            }
        } else {
            #pragma unroll
            for (int p = 0; p < 2; ++p) {
                int q  = t + (p << 8);
                int mm = q >> 2;
                int kv = (q & 3) << 2;
                float4 v = make_float4(0.f, 0.f, 0.f, 0.f);
                int m = m0 + mm;
                if (m < M && kv < klen)
                    v = *(const float4*)(Ag + (size_t)m * DIS + k0 + kv);
                As[kv + 0][mm] = v.x;
                As[kv + 1][mm] = v.y;
                As[kv + 2][mm] = v.z;
                As[kv + 3][mm] = v.w;
            }
        }
        {
            int kk = t >> 4, jv = (t & 15) << 2;
            float4 v = make_float4(0.f, 0.f, 0.f, 0.f);
            if (kk < klen) v = *(const float4*)(B + (size_t)(k0 + kk) * LAT + jv);
            *(float4*)&Bs[kk][jv] = v;
        }
        __syncthreads();
        #pragma unroll
        for (int kk = 0; kk < 16; ++kk) {
            float4 a0 = *(float4*)&As[kk][ty * 8];
            float4 a1 = *(float4*)&As[kk][ty * 8 + 4];
            float4 bv = *(float4*)&Bs[kk][tx * 4];
            float af[8] = {a0.x, a0.y, a0.z, a0.w, a1.x, a1.y, a1.z, a1.w};
            float bf[4] = {bv.x, bv.y, bv.z, bv.w};
            #pragma unroll
            for (int i = 0; i < 8; ++i)
                #pragma unroll
                for (int j = 0; j < 4; ++j) acc[i][j] = fmaf(af[i], bf[j], acc[i][j]);
        }
        __syncthreads();
    }
    #pragma unroll
    for (int i = 0; i < 8; ++i) {
        int m = m0 + ty * 8 + i;
        if (m < M) {
            #pragma unroll
            for (int j = 0; j < 4; ++j)
                atomicAdd(&C[(size_t)m * LAT + tx * 4 + j], acc[i][j]);
        }
    }
}

__global__ __launch_bounds__(256) void update_f32(const float* __restrict__ gA,
                                                  const float* __restrict__ gB,
                                                  const float* __restrict__ inv_c,
                                                  const float* __restrict__ inv_d,
                                                  const float* __restrict__ circ,
                                                  const float* __restrict__ dis,
                                                  float* __restrict__ Bc, float* __restrict__ Bd,
                                                  float* __restrict__ acc) {
    int wid = threadIdx.x >> 6, lane = threadIdx.x & 63;
    int r = blockIdx.x * 4 + wid;
    if (r >= CIRC + DIS) return;
    float raw, ego, scale;
    if (r < CIRC) {
        scale = inv_c[r];
        raw = scale * gA[(size_t)r * LAT + lane];
        ego = circ[(size_t)r * LAT + lane];
    } else {
        int c = r - CIRC;
        scale = inv_d[c];
        raw = scale * gB[(size_t)c * LAT + lane];
        ego = dis[(size_t)c * LAT + lane];
    }
    float dot = raw * ego, n1 = raw * raw, n2 = ego * ego;
    #pragma unroll
    for (int o = 32; o; o >>= 1) {
        dot += __shfl_down(dot, o);
        n1  += __shfl_down(n1, o);
        n2  += __shfl_down(n2, o);
    }
    dot = __shfl(dot, 0); n1 = __shfl(n1, 0); n2 = __shfl(n2, 0);
    float w = dot / (fmaxf(sqrtf(n1), EPSF) * fmaxf(sqrtf(n2), EPSF));
    float val = w * raw;
    acc[(size_t)r * LAT + lane] += val;
    if (r < CIRC) Bc[(size_t)r * LAT + lane] = scale * val;
    else          Bd[(size_t)(r - CIRC) * LAT + lane] = scale * val;
}

// ================= launcher =================

extern "C" void kernel_launch(void* const* d_in, const int* in_sizes, int n_in,
                              void* d_out, int out_size, void* d_ws, size_t ws_size,
                              hipStream_t stream) {
    const float* A    = (const float*)d_in[0];
    const float* circ = (const float*)d_in[1];
    const float* dis  = (const float*)d_in[2];
    const float* reCD = (const float*)d_in[3];
    float* out = (float*)d_out;
    char* w = (char*)d_ws;

    // bf16 path layout (bytes); Abf last with ~1 MB slack for benign OOB frag reads
    const size_t NEED = 168400000ull;
    if (ws_size >= NEED) {
        float*  dc  = (float*) (w + 0);           //    40,000
        float*  dd  = (float*) (w + 40000);       //    16,000
        float*  acc = (float*) (w + 64000);       // 3,584,000
        __bf16* Bc  = (__bf16*)(w + 3648000);     // 1,280,000
        __bf16* Bd  = (__bf16*)(w + 4928000);     //   512,000
        float*  P1  = (float*) (w + 5440000);     // 40,960,000 (16 x CIRC x 64)
        float*  P2  = (float*) (w + 46400000);    // 40,960,000 (40 x DIS x 64)
        __bf16* Abf = (__bf16*)(w + 87360000);    // 80,000,000 (+ ~1 MB slack)

        hipMemsetAsync(dd, 0, DIS * sizeof(float), stream);
        split_kernel<<<2500, 256, 0, stream>>>(A, Abf, dc);
        colsum_bf16<<<dim3(16, 40), 256, 0, stream>>>(Abf, dd);
        inv_kernel<<<55, 256, 0, stream>>>(dc, dd);
        init2<<<3500, 256, 0, stream>>>(circ, dis, dc, dd, Bc, Bd, acc);

        for (int layer = 0; layer < 3; ++layer) {
            gemm1_bf16<<<dim3(79, S1), 256, 0, stream>>>(Abf, Bd, P1);
            gemm2_bf16<<<dim3(32, S2), 256, 0, stream>>>(Abf, Bc, P2);
            update2<<<3500, 256, 0, stream>>>(P1, P2, dc, dd, circ, dis, Bc, Bd, acc);
        }

        hipMemcpyAsync(out, acc, (size_t)(CIRC + DIS) * LAT * sizeof(float),
                       hipMemcpyDeviceToDevice, stream);
        predict_kernel<<<dim3(79, 63), 256, 0, stream>>>(acc, reCD, out + (size_t)(CIRC + DIS) * LAT);
    } else {
        float* ws  = (float*)d_ws;
        float* dc  = ws;
        float* dd  = ws + 10000;
        float* Bc  = ws + 14000;
        float* Bd  = ws + 654000;
        float* gA  = ws + 910000;
        float* gB  = ws + 1550000;
        float* acc = ws + 1806000;

        hipMemsetAsync(dd, 0, DIS * sizeof(float), stream);
        rowsum_kernel<<<2500, 256, 0, stream>>>(A, dc);
        colsum_f32<<<dim3(16, 40), 256, 0, stream>>>(A, dd);
        inv_kernel<<<55, 256, 0, stream>>>(dc, dd);
        init_f32<<<3500, 256, 0, stream>>>(circ, dis, dc, dd, Bc, Bd, acc);

        for (int layer = 0; layer < 3; ++layer) {
            hipMemsetAsync(gA, 0, (size_t)(CIRC + DIS) * LAT * sizeof(float), stream);
            gemm_tn<false><<<dim3(79, 8), 256, 0, stream>>>(A, Bd, gA, CIRC, DIS, 500);
            gemm_tn<true><<<dim3(32, 16), 256, 0, stream>>>(A, Bc, gB, DIS, CIRC, 625);
            update_f32<<<3500, 256, 0, stream>>>(gA, gB, dc, dd, circ, dis, Bc, Bd, acc);
        }

        hipMemcpyAsync(out, acc, (size_t)(CIRC + DIS) * LAT * sizeof(float),
                       hipMemcpyDeviceToDevice, stream);
        predict_kernel<<<dim3(79, 63), 256, 0, stream>>>(acc, reCD, out + (size_t)(CIRC + DIS) * LAT);
    }
}